// Round 5
// baseline (219.452 us; speedup 1.0000x reference)
//
#include <hip/hip_runtime.h>
#include <math.h>

#define LOG2E 1.44269504088896340736f
#define LN2   0.69314718055994530942f

typedef _Float16 half8 __attribute__((ext_vector_type(8)));
typedef float f32x4v __attribute__((ext_vector_type(4)));

#define AROW 24   // halves per LDS row (48B): 16B-aligned frag reads

// ---------------------------------------------------------------------------
// kA: Lout[fb][b][g] = sum_{f in 512-range} exp( dot16(A[:,f], T[:,g]) )
// via mfma_f32_16x16x32_f16 with [Ah|Al] x [Th|Th] + [Ah|Al] x [Tl|0].
// grid (8 gb, 4 fb, 32 b), block 256 (4 waves; wave owns 64 g-columns -> each
// ds_read_b128 A-fragment feeds 4 MFMA-pairs: LDS traffic halved vs 32 g).
// Double-buffered LDS staging: global prefetch overlaps compute, 1 barrier/chunk.
// ---------------------------------------------------------------------------
template <bool ATOMIC>
__global__ __launch_bounds__(256, 4) void kA(const float* __restrict__ data,
                                             const float* __restrict__ attn,
                                             float* __restrict__ Lout) {
    __shared__ _Float16 AhB[2][128 * AROW];
    __shared__ _Float16 AlB[2][128 * AROW];
    const int tid = threadIdx.x;
    const int b = blockIdx.z, fb = blockIdx.y, gb = blockIdx.x;
    const int wave = tid >> 6, lane = tid & 63;
    const int n = lane & 15, q = lane >> 4;
    const int s0 = (q & 1) * 8;

    // B fragments (loop-invariant), 4 column-tiles per wave.
    const float* Tb = attn + (size_t)b * 16 * 2048;
    half8 B1[4], B2[4];
#pragma unroll
    for (int ct = 0; ct < 4; ++ct) {
        const int g = gb * 256 + wave * 64 + ct * 16 + n;
        half8 bh, bl;
#pragma unroll
        for (int j = 0; j < 8; ++j) {
            float x = Tb[(size_t)(s0 + j) * 2048 + g] * LOG2E;
            _Float16 h = (_Float16)x;
            _Float16 l = (_Float16)(x - (float)h);
            bh[j] = h;
            bl[j] = (q < 2) ? l : (_Float16)0.0f;
        }
        B1[ct] = bh;
        B2[ct] = bl;
    }

    f32x4v cs[4];
#pragma unroll
    for (int ct = 0; ct < 4; ++ct) cs[ct] = (f32x4v){0.f, 0.f, 0.f, 0.f};

    const float* Ab = data + (size_t)b * 16 * 2048 + fb * 512;
    const int fst = tid & 127;       // f-row within chunk
    const int sh  = (tid >> 7) * 8;  // s-half this thread stages

    const _Float16* ap0 = ((q < 2) ? &AhB[0][0] : &AlB[0][0]) + n * AROW + s0;
    const _Float16* ap1 = ((q < 2) ? &AhB[1][0] : &AlB[1][0]) + n * AROW + s0;

    // Prologue: stage chunk 0 into buffer 0.
    {
        const float* Ac = Ab;
        half8 hv, lv;
#pragma unroll
        for (int j = 0; j < 8; ++j) {
            float x = Ac[(size_t)(sh + j) * 2048 + fst];
            _Float16 h = (_Float16)x;
            hv[j] = h;
            lv[j] = (_Float16)(x - (float)h);
        }
        *(half8*)(&AhB[0][fst * AROW + sh]) = hv;
        *(half8*)(&AlB[0][fst * AROW + sh]) = lv;
    }
    __syncthreads();

    for (int c = 0; c < 4; ++c) {
        // Prefetch next chunk (global loads overlap this chunk's compute).
        float xr[8];
        if (c < 3) {
            const float* Ac = Ab + (c + 1) * 128;
#pragma unroll
            for (int j = 0; j < 8; ++j)
                xr[j] = Ac[(size_t)(sh + j) * 2048 + fst];
        }

        const _Float16* aptr = (c & 1) ? ap1 : ap0;
#pragma unroll
        for (int rt = 0; rt < 8; ++rt) {
            half8 af = *(const half8*)(aptr + rt * 16 * AROW);
            f32x4v Cr[4];
#pragma unroll
            for (int ct = 0; ct < 4; ++ct) {
                f32x4v t = {0.f, 0.f, 0.f, 0.f};
                t = __builtin_amdgcn_mfma_f32_16x16x32_f16(af, B1[ct], t, 0, 0, 0);
                t = __builtin_amdgcn_mfma_f32_16x16x32_f16(af, B2[ct], t, 0, 0, 0);
                Cr[ct] = t;
            }
#pragma unroll
            for (int ct = 0; ct < 4; ++ct) {
                cs[ct][0] += __builtin_amdgcn_exp2f(Cr[ct][0]);
                cs[ct][1] += __builtin_amdgcn_exp2f(Cr[ct][1]);
                cs[ct][2] += __builtin_amdgcn_exp2f(Cr[ct][2]);
                cs[ct][3] += __builtin_amdgcn_exp2f(Cr[ct][3]);
            }
        }

        if (c < 3) {
            half8 hv, lv;
#pragma unroll
            for (int j = 0; j < 8; ++j) {
                _Float16 h = (_Float16)xr[j];
                hv[j] = h;
                lv[j] = (_Float16)(xr[j] - (float)h);
            }
            const int nb = (c + 1) & 1;
            *(half8*)(&AhB[nb][fst * AROW + sh]) = hv;
            *(half8*)(&AlB[nb][fst * AROW + sh]) = lv;
        }
        __syncthreads();
    }

#pragma unroll
    for (int ct = 0; ct < 4; ++ct) {
        float v = cs[ct][0] + cs[ct][1] + cs[ct][2] + cs[ct][3];
        v += __shfl_xor(v, 16);
        v += __shfl_xor(v, 32);
        if (q == 0) {
            const int g = gb * 256 + wave * 64 + ct * 16 + n;
            if (ATOMIC)
                atomicAdd(&Lout[(size_t)b * 2048 + g], v);
            else
                Lout[((size_t)fb * 32 + b) * 2048 + g] = v;
        }
    }
}

// ---------------------------------------------------------------------------
// kTail: per (256-g segment, b): L = ln2*log2(sum Lpart), c-partials, M-partials.
// grid (8, 32), block 256.
// ---------------------------------------------------------------------------
#define TP 260
__global__ __launch_bounds__(256) void kTail(const float* __restrict__ attn,
                                             const float* __restrict__ Lpart, int nparts,
                                             float* __restrict__ Mpart,
                                             float* __restrict__ cpart) {
    __shared__ float Tsh[16 * TP];   // 16.6 KB
    __shared__ float Lsh[256];
    __shared__ float red[16][17];
    const int tid = threadIdx.x;
    const int seg = blockIdx.x, b = blockIdx.y;
    const int g0 = seg * 256;

#pragma unroll
    for (int s = 0; s < 16; ++s)
        Tsh[s * TP + tid] = attn[(size_t)(b * 16 + s) * 2048 + g0 + tid];
    {
        float sum = 0.f;
        for (int p = 0; p < nparts; ++p)
            sum += Lpart[((size_t)p * 32 + b) * 2048 + g0 + tid];
        Lsh[tid] = LN2 * __builtin_amdgcn_logf(sum);
    }
    __syncthreads();

    // c-partial: t = tid&15 over a 16-g subrange
    {
        const int t = tid & 15, i = tid >> 4;
        float acc = 0.f;
#pragma unroll
        for (int k = 0; k < 4; ++k) {
            float4 l  = *(const float4*)(Lsh + i * 16 + k * 4);
            float4 tv = *(const float4*)(Tsh + t * TP + i * 16 + k * 4);
            acc += l.x * tv.x + l.y * tv.y + l.z * tv.z + l.w * tv.w;
        }
        red[t][i] = acc;
    }
    __syncthreads();
    if (tid < 16) {
        float s = 0.f;
#pragma unroll
        for (int k = 0; k < 16; ++k) s += red[tid][k];
        cpart[((size_t)seg * 32 + b) * 16 + tid] = s;
    }

    // M-partial: thread = (s,t)
    {
        const int s = tid >> 4, t = tid & 15;
        float a0 = 0.f, a1 = 0.f;
#pragma unroll 4
        for (int qk = 0; qk < 32; ++qk) {
            float4 x = *(const float4*)(Tsh + s * TP + qk * 8);
            float4 y = *(const float4*)(Tsh + t * TP + qk * 8);
            a0 += x.x * y.x + x.y * y.y + x.z * y.z + x.w * y.w;
            float4 x2 = *(const float4*)(Tsh + s * TP + qk * 8 + 4);
            float4 y2 = *(const float4*)(Tsh + t * TP + qk * 8 + 4);
            a1 += x2.x * y2.x + x2.y * y2.y + x2.z * y2.z + x2.w * y2.w;
        }
        Mpart[((size_t)seg * 32 + b) * 256 + tid] = a0 + a1;
    }
}

// ---------------------------------------------------------------------------
// kC2: fold M/c partials with W,bias (redundant per block, cheap) + epilogue.
// grid (8, 32), block 256.
// ---------------------------------------------------------------------------
__global__ __launch_bounds__(256) void kC2(const float* __restrict__ data,
                                           const float* __restrict__ Mpart,
                                           const float* __restrict__ cpart,
                                           const float* __restrict__ W,
                                           const float* __restrict__ bias,
                                           float* __restrict__ out) {
    __shared__ float Msh[256];
    __shared__ float csh[16];
    __shared__ float Vsh[256];
    __shared__ float w0sh[16];
    const int tid = threadIdx.x;
    const int b = blockIdx.y;
    const int f = blockIdx.x * 256 + tid;

    {
        float m = 0.f;
#pragma unroll
        for (int p = 0; p < 8; ++p) m += Mpart[((size_t)p * 32 + b) * 256 + tid];
        Msh[tid] = m;
        if (tid < 16) {
            float c = 0.f;
#pragma unroll
            for (int p = 0; p < 8; ++p) c += cpart[((size_t)p * 32 + b) * 16 + tid];
            csh[tid] = c;
        }
    }
    __syncthreads();
    {
        const int s = tid >> 4, j = tid & 15;
        float acc = 0.f;
#pragma unroll
        for (int t = 0; t < 16; ++t) acc += Msh[s * 16 + t] * W[j * 32 + t];
        Vsh[s * 16 + j] = acc + W[j * 32 + 16 + s];
        if (s == 0) {
            float w0 = 0.f;
#pragma unroll
            for (int t = 0; t < 16; ++t) w0 += csh[t] * W[j * 32 + t];
            w0sh[j] = bias[j] - w0;
        }
    }
    __syncthreads();

    float As[16];
#pragma unroll
    for (int s = 0; s < 16; ++s)
        As[s] = data[(size_t)(b * 16 + s) * 2048 + f];
#pragma unroll
    for (int j = 0; j < 16; ++j) {
        float p = w0sh[j];
#pragma unroll
        for (int s = 0; s < 16; ++s) p += As[s] * Vsh[s * 16 + j];
        float e = __builtin_amdgcn_exp2f(-LOG2E * p);
        float gate = __builtin_amdgcn_rcpf(1.0f + e);
        size_t r = (size_t)(j * 32 + b) * 2048 + f;
        out[r] = gate * data[r];
    }
}

extern "C" void kernel_launch(void* const* d_in, const int* in_sizes, int n_in,
                              void* d_out, int out_size, void* d_ws, size_t ws_size,
                              hipStream_t stream) {
    const float* data = (const float*)d_in[0];
    const float* attn = (const float*)d_in[1];
    const float* W    = (const float*)d_in[2];
    const float* bias = (const float*)d_in[3];
    float* out = (float*)d_out;
    float* ws  = (float*)d_ws;

    // big layout: Lpart[4][32][2048] | Mpart[8][32][256] | cpart[8][32][16]
    const size_t LP = 4 * 32 * 2048;              // 262144
    const size_t need_big = LP + 65536 + 4096;

    if (ws_size >= need_big * sizeof(float)) {
        float* Lpart = ws;
        float* Mpart = ws + LP;
        float* cpart = Mpart + 65536;
        kA<false><<<dim3(8, 4, 32), 256, 0, stream>>>(data, attn, Lpart);
        kTail<<<dim3(8, 32), 256, 0, stream>>>(attn, Lpart, 4, Mpart, cpart);
        kC2<<<dim3(8, 32), 256, 0, stream>>>(data, Mpart, cpart, W, bias, out);
    } else {
        float* Lsum  = ws;            // 65536
        float* Mpart = ws + 65536;
        float* cpart = Mpart + 65536;
        hipMemsetAsync(Lsum, 0, 65536 * sizeof(float), stream);
        kA<true><<<dim3(8, 4, 32), 256, 0, stream>>>(data, attn, Lsum);
        kTail<<<dim3(8, 32), 256, 0, stream>>>(attn, Lsum, 1, Mpart, cpart);
        kC2<<<dim3(8, 32), 256, 0, stream>>>(data, Mpart, cpart, W, bias, out);
    }
}

// Round 6
// 98.301 us; speedup vs baseline: 2.2324x; 2.2324x over previous
//
#include <hip/hip_runtime.h>
#include <math.h>

#define LOG2E 1.44269504088896340736f
#define LN2   0.69314718055994530942f

typedef _Float16 half8 __attribute__((ext_vector_type(8)));
typedef float f32x4v __attribute__((ext_vector_type(4)));

#define TROW 24   // halves per LDS T-row (48B): 16B-aligned b128, <=2-way banks

// ---------------------------------------------------------------------------
// kA (flipped): wave owns 64 f-rows (4 invariant A-frags, [Ah|Al] along K);
// iterates 16 g-tiles reading T hi/lo fragments from LDS.
//   MFMA1: A1 x [Th|Th] = Ah·Th + Al·Th ; MFMA2: A1 x [Tl|0] = Ah·Tl
// (drops only Al·Tl ~ 2^-22 — same math as rounds 3-5).
// Column sums: per-tile shfl over quads -> Lw[wave][g], block-reduce at end.
// grid (8 gs, 8 fb, 32 b) = 2048 blocks, 256 thr. Live regs ~50: no spill.
// ---------------------------------------------------------------------------
template <bool ATOMIC>
__global__ __launch_bounds__(256, 4) void kA(const float* __restrict__ data,
                                             const float* __restrict__ attn,
                                             float* __restrict__ Lout) {
    __shared__ _Float16 ThL[256 * TROW];  // 12 KB
    __shared__ _Float16 TlL[256 * TROW];  // 12 KB
    __shared__ _Float16 zeroH[8];
    __shared__ float Lw[4][256];          // 4 KB
    const int tid = threadIdx.x;
    const int b = blockIdx.z, fb = blockIdx.y, gs = blockIdx.x;
    const int wave = tid >> 6, lane = tid & 63;
    const int n = lane & 15, q = lane >> 4;
    const int g0 = gs * 256;

    // ---- Stage T hi/lo (pre-scaled by log2e) into [g][s] layout ----
    {
        const float* Tb = attn + (size_t)b * 16 * 2048 + g0;
        const int gl = tid >> 1;        // 0..127
        const int sh = (tid & 1) * 8;   // s-half
#pragma unroll
        for (int p = 0; p < 2; ++p) {
            const int g = gl + p * 128;
            half8 hv, lv;
#pragma unroll
            for (int j = 0; j < 8; ++j) {
                float x = Tb[(size_t)(sh + j) * 2048 + g] * LOG2E;
                _Float16 h = (_Float16)x;
                hv[j] = h;
                lv[j] = (_Float16)(x - (float)h);
            }
            *(half8*)(ThL + g * TROW + sh) = hv;
            *(half8*)(TlL + g * TROW + sh) = lv;
        }
        if (tid < 8) zeroH[tid] = (_Float16)0.0f;
    }

    // ---- Invariant A-fragments: [Ah|Al] along K (q<2: hi, q>=2: lo) ----
    half8 A1[4];
    {
        const float* Ab = data + (size_t)b * 16 * 2048;
        const int frow = fb * 256 + wave * 64;
#pragma unroll
        for (int r = 0; r < 4; ++r) {
            half8 a;
#pragma unroll
            for (int j = 0; j < 8; ++j) {
                const int s = (q & 1) * 8 + j;
                float x = Ab[(size_t)s * 2048 + frow + r * 16 + n];
                _Float16 h = (_Float16)x;
                a[j] = (q < 2) ? h : (_Float16)(x - (float)h);
            }
            A1[r] = a;
        }
    }
    __syncthreads();

    // B1: all lanes read ThL at s=(q&1)*8+j.  B2: q<2 read TlL at s=q*8+j,
    // q>=2 read the shared zero fragment (wave-broadcast, free).
    const _Float16* b1base = ThL + (q & 1) * 8;
    const _Float16* b2base = (q < 2) ? (TlL + q * 8) : zeroH;
    const int b2stride = (q < 2) ? TROW : 0;

    for (int gt = 0; gt < 16; ++gt) {
        const int gp = gt * 16 + n;
        half8 B1 = *(const half8*)(b1base + gp * TROW);
        half8 B2 = *(const half8*)(b2base + gp * b2stride);
        float sum = 0.f;
#pragma unroll
        for (int r = 0; r < 4; ++r) {
            f32x4v C = {0.f, 0.f, 0.f, 0.f};
            C = __builtin_amdgcn_mfma_f32_16x16x32_f16(A1[r], B1, C, 0, 0, 0);
            C = __builtin_amdgcn_mfma_f32_16x16x32_f16(A1[r], B2, C, 0, 0, 0);
            sum += __builtin_amdgcn_exp2f(C[0]) + __builtin_amdgcn_exp2f(C[1])
                 + __builtin_amdgcn_exp2f(C[2]) + __builtin_amdgcn_exp2f(C[3]);
        }
        sum += __shfl_xor(sum, 16);
        sum += __shfl_xor(sum, 32);
        if (q == 0) Lw[wave][gp] = sum;
    }
    __syncthreads();

    {
        const float v = Lw[0][tid] + Lw[1][tid] + Lw[2][tid] + Lw[3][tid];
        if (ATOMIC)
            atomicAdd(&Lout[(size_t)b * 2048 + g0 + tid], v);
        else
            Lout[((size_t)fb * 32 + b) * 2048 + g0 + tid] = v;
    }
}

// ---------------------------------------------------------------------------
// kTail: per (256-g segment, b): L = ln2*log2(sum Lpart), c-partials, M-partials.
// grid (8, 32), block 256.
// ---------------------------------------------------------------------------
#define TP 260
__global__ __launch_bounds__(256) void kTail(const float* __restrict__ attn,
                                             const float* __restrict__ Lpart, int nparts,
                                             float* __restrict__ Mpart,
                                             float* __restrict__ cpart) {
    __shared__ float Tsh[16 * TP];   // 16.6 KB
    __shared__ float Lsh[256];
    __shared__ float red[16][17];
    const int tid = threadIdx.x;
    const int seg = blockIdx.x, b = blockIdx.y;
    const int g0 = seg * 256;

#pragma unroll
    for (int s = 0; s < 16; ++s)
        Tsh[s * TP + tid] = attn[(size_t)(b * 16 + s) * 2048 + g0 + tid];
    {
        float sum = 0.f;
        for (int p = 0; p < nparts; ++p)
            sum += Lpart[((size_t)p * 32 + b) * 2048 + g0 + tid];
        Lsh[tid] = LN2 * __builtin_amdgcn_logf(sum);
    }
    __syncthreads();

    // c-partial: t = tid&15 over a 16-g subrange
    {
        const int t = tid & 15, i = tid >> 4;
        float acc = 0.f;
#pragma unroll
        for (int k = 0; k < 4; ++k) {
            float4 l  = *(const float4*)(Lsh + i * 16 + k * 4);
            float4 tv = *(const float4*)(Tsh + t * TP + i * 16 + k * 4);
            acc += l.x * tv.x + l.y * tv.y + l.z * tv.z + l.w * tv.w;
        }
        red[t][i] = acc;
    }
    __syncthreads();
    if (tid < 16) {
        float s = 0.f;
#pragma unroll
        for (int k = 0; k < 16; ++k) s += red[tid][k];
        cpart[((size_t)seg * 32 + b) * 16 + tid] = s;
    }

    // M-partial: thread = (s,t)
    {
        const int s = tid >> 4, t = tid & 15;
        float a0 = 0.f, a1 = 0.f;
#pragma unroll 4
        for (int qk = 0; qk < 32; ++qk) {
            float4 x = *(const float4*)(Tsh + s * TP + qk * 8);
            float4 y = *(const float4*)(Tsh + t * TP + qk * 8);
            a0 += x.x * y.x + x.y * y.y + x.z * y.z + x.w * y.w;
            float4 x2 = *(const float4*)(Tsh + s * TP + qk * 8 + 4);
            float4 y2 = *(const float4*)(Tsh + t * TP + qk * 8 + 4);
            a1 += x2.x * y2.x + x2.y * y2.y + x2.z * y2.z + x2.w * y2.w;
        }
        Mpart[((size_t)seg * 32 + b) * 256 + tid] = a0 + a1;
    }
}

// ---------------------------------------------------------------------------
// kC2: fold M/c partials with W,bias (redundant per block, cheap) + epilogue.
// grid (8, 32), block 256.
// ---------------------------------------------------------------------------
__global__ __launch_bounds__(256) void kC2(const float* __restrict__ data,
                                           const float* __restrict__ Mpart,
                                           const float* __restrict__ cpart,
                                           const float* __restrict__ W,
                                           const float* __restrict__ bias,
                                           float* __restrict__ out) {
    __shared__ float Msh[256];
    __shared__ float csh[16];
    __shared__ float Vsh[256];
    __shared__ float w0sh[16];
    const int tid = threadIdx.x;
    const int b = blockIdx.y;
    const int f = blockIdx.x * 256 + tid;

    {
        float m = 0.f;
#pragma unroll
        for (int p = 0; p < 8; ++p) m += Mpart[((size_t)p * 32 + b) * 256 + tid];
        Msh[tid] = m;
        if (tid < 16) {
            float c = 0.f;
#pragma unroll
            for (int p = 0; p < 8; ++p) c += cpart[((size_t)p * 32 + b) * 16 + tid];
            csh[tid] = c;
        }
    }
    __syncthreads();
    {
        const int s = tid >> 4, j = tid & 15;
        float acc = 0.f;
#pragma unroll
        for (int t = 0; t < 16; ++t) acc += Msh[s * 16 + t] * W[j * 32 + t];
        Vsh[s * 16 + j] = acc + W[j * 32 + 16 + s];
        if (s == 0) {
            float w0 = 0.f;
#pragma unroll
            for (int t = 0; t < 16; ++t) w0 += csh[t] * W[j * 32 + t];
            w0sh[j] = bias[j] - w0;
        }
    }
    __syncthreads();

    float As[16];
#pragma unroll
    for (int s = 0; s < 16; ++s)
        As[s] = data[(size_t)(b * 16 + s) * 2048 + f];
#pragma unroll
    for (int j = 0; j < 16; ++j) {
        float p = w0sh[j];
#pragma unroll
        for (int s = 0; s < 16; ++s) p += As[s] * Vsh[s * 16 + j];
        float e = __builtin_amdgcn_exp2f(-LOG2E * p);
        float gate = __builtin_amdgcn_rcpf(1.0f + e);
        size_t r = (size_t)(j * 32 + b) * 2048 + f;
        out[r] = gate * data[r];
    }
}

extern "C" void kernel_launch(void* const* d_in, const int* in_sizes, int n_in,
                              void* d_out, int out_size, void* d_ws, size_t ws_size,
                              hipStream_t stream) {
    const float* data = (const float*)d_in[0];
    const float* attn = (const float*)d_in[1];
    const float* W    = (const float*)d_in[2];
    const float* bias = (const float*)d_in[3];
    float* out = (float*)d_out;
    float* ws  = (float*)d_ws;

    // big layout: Lpart[8][32][2048] | Mpart[8][32][256] | cpart[8][32][16]
    const size_t LP = 8 * 32 * 2048;              // 524288
    const size_t need_big = LP + 65536 + 4096;

    if (ws_size >= need_big * sizeof(float)) {
        float* Lpart = ws;
        float* Mpart = ws + LP;
        float* cpart = Mpart + 65536;
        kA<false><<<dim3(8, 8, 32), 256, 0, stream>>>(data, attn, Lpart);
        kTail<<<dim3(8, 32), 256, 0, stream>>>(attn, Lpart, 8, Mpart, cpart);
        kC2<<<dim3(8, 32), 256, 0, stream>>>(data, Mpart, cpart, W, bias, out);
    } else {
        float* Lsum  = ws;            // 65536
        float* Mpart = ws + 65536;
        float* cpart = Mpart + 65536;
        hipMemsetAsync(Lsum, 0, 65536 * sizeof(float), stream);
        kA<true><<<dim3(8, 8, 32), 256, 0, stream>>>(data, attn, Lsum);
        kTail<<<dim3(8, 32), 256, 0, stream>>>(attn, Lsum, 1, Mpart, cpart);
        kC2<<<dim3(8, 32), 256, 0, stream>>>(data, Mpart, cpart, W, bias, out);
    }
}